// Round 1
// baseline (152.033 us; speedup 1.0000x reference)
//
#include <hip/hip_runtime.h>

#define B_   32
#define H_   640
#define W_   368
#define OH   634          // H - 6
#define OW   362          // W - 6
#define CHUNK 56          // output rows per block (multiple of 7)
#define NSTRIPE 6         // ceil(362/64)
#define NCHUNK 12         // ceil(634/56)

// d_ws layout (floats): [0..31] per-batch max of target, [32] S-sum accumulator

__global__ __launch_bounds__(256) void k_max(const float* __restrict__ tgt,
                                             float* __restrict__ ws) {
    const int b   = blockIdx.x >> 3;
    const int seg = blockIdx.x & 7;
    const int perseg = (H_ * W_) / 8;          // 29440
    const float4* p = (const float4*)(tgt + (size_t)b * (H_ * W_) + (size_t)seg * perseg);
    const int n4 = perseg / 4;                 // 7360
    float m = 0.0f;
    for (int i = threadIdx.x; i < n4; i += 256) {
        float4 v = p[i];
        m = fmaxf(m, fmaxf(fmaxf(v.x, v.y), fmaxf(v.z, v.w)));
    }
    #pragma unroll
    for (int off = 32; off; off >>= 1)
        m = fmaxf(m, __shfl_down(m, off, 64));
    __shared__ float sm[4];
    const int lane = threadIdx.x & 63, wv = threadIdx.x >> 6;
    if (lane == 0) sm[wv] = m;
    __syncthreads();
    if (threadIdx.x == 0) {
        m = fmaxf(fmaxf(sm[0], sm[1]), fmaxf(sm[2], sm[3]));
        atomicMax((int*)ws + b, __float_as_int(m));   // inputs >= 0 -> int cmp == float cmp
    }
}

__global__ __launch_bounds__(64) void k_ssim(const float* __restrict__ X,
                                             const float* __restrict__ Y,
                                             const float* __restrict__ ws,
                                             float* __restrict__ wsum) {
    const int sx = blockIdx.x;                 // column stripe
    const int cy = blockIdx.y;                 // row chunk
    const int b  = blockIdx.z;                 // batch
    const int c  = sx * 64 + threadIdx.x;      // output column
    const int r0 = cy * CHUNK;
    const int outRows = min(CHUNK, OH - r0);
    const bool colOK = (c < OW);

    const float dr = ws[b];
    float C1 = 0.01f * dr; C1 *= C1;
    float C2 = 0.03f * dr; C2 *= C2;

    const float* xb = X + (size_t)b * (H_ * W_);
    const float* yb = Y + (size_t)b * (H_ * W_);

    float rx[7], ry[7], rxx[7], ryy[7], rxy[7];
    float tx = 0, ty = 0, txx = 0, tyy = 0, txy = 0;
    float acc = 0.0f;

    const float inv_np  = 1.0f / 49.0f;
    const float covn    = 49.0f / 48.0f;

    if (colOK) {
        // prime: rows r0 .. r0+5 -> ring slots 0..5
        #pragma unroll
        for (int p = 0; p < 6; ++p) {
            const float* xr = xb + (size_t)(r0 + p) * W_ + c;
            const float* yr = yb + (size_t)(r0 + p) * W_ + c;
            float hx = 0, hy = 0, hxx = 0, hyy = 0, hxy = 0;
            #pragma unroll
            for (int k = 0; k < 7; ++k) {
                float xv = xr[k], yv = yr[k];
                hx += xv; hy += yv;
                hxx = fmaf(xv, xv, hxx);
                hyy = fmaf(yv, yv, hyy);
                hxy = fmaf(xv, yv, hxy);
            }
            rx[p] = hx; ry[p] = hy; rxx[p] = hxx; ryy[p] = hyy; rxy[p] = hxy;
            tx += hx; ty += hy; txx += hxx; tyy += hyy; txy += hxy;
        }

        for (int ii = 0; ii < outRows; ii += 7) {
            #pragma unroll
            for (int p = 0; p < 7; ++p) {     // slot indices compile-time: ii % 7 == 0
                const int i = ii + p;         // output row within chunk
                if (i >= outRows) break;      // uniform across block
                const float* xr = xb + (size_t)(r0 + i + 6) * W_ + c;
                const float* yr = yb + (size_t)(r0 + i + 6) * W_ + c;
                float hx = 0, hy = 0, hxx = 0, hyy = 0, hxy = 0;
                #pragma unroll
                for (int k = 0; k < 7; ++k) {
                    float xv = xr[k], yv = yr[k];
                    hx += xv; hy += yv;
                    hxx = fmaf(xv, xv, hxx);
                    hyy = fmaf(yv, yv, hyy);
                    hxy = fmaf(xv, yv, hxy);
                }
                tx += hx; ty += hy; txx += hxx; tyy += hyy; txy += hxy;

                const float ux  = tx  * inv_np;
                const float uy  = ty  * inv_np;
                const float uxx = txx * inv_np;
                const float uyy = tyy * inv_np;
                const float uxy = txy * inv_np;
                const float vx  = covn * (uxx - ux * ux);
                const float vy  = covn * (uyy - uy * uy);
                const float vxy = covn * (uxy - ux * uy);
                const float A1  = 2.0f * ux * uy + C1;
                const float A2  = 2.0f * vxy + C2;
                const float B1  = ux * ux + uy * uy + C1;
                const float B2  = vx + vy + C2;
                acc += (A1 * A2) / (B1 * B2);

                // retire oldest (row i, slot i%7 == p), insert new (row i+6, slot (p+6)%7)
                tx -= rx[p]; ty -= ry[p]; txx -= rxx[p]; tyy -= ryy[p]; txy -= rxy[p];
                const int sn = (p + 6) % 7;
                rx[sn] = hx; ry[sn] = hy; rxx[sn] = hxx; ryy[sn] = hyy; rxy[sn] = hxy;
            }
        }
    }

    // single-wave block reduction (invalid columns contribute 0)
    #pragma unroll
    for (int off = 32; off; off >>= 1)
        acc += __shfl_down(acc, off, 64);
    if (threadIdx.x == 0)
        atomicAdd(wsum, acc);
}

__global__ void k_fin(const float* __restrict__ wsum, float* __restrict__ out) {
    out[0] = 1.0f - wsum[0] * (1.0f / (32.0f * 634.0f * 362.0f));
}

extern "C" void kernel_launch(void* const* d_in, const int* in_sizes, int n_in,
                              void* d_out, int out_size, void* d_ws, size_t ws_size,
                              hipStream_t stream) {
    const float* X = (const float*)d_in[0];   // 'output'
    const float* Y = (const float*)d_in[1];   // 'target'
    float* ws = (float*)d_ws;

    hipMemsetAsync(d_ws, 0, 33 * sizeof(float), stream);
    k_max<<<dim3(256), dim3(256), 0, stream>>>(Y, ws);
    k_ssim<<<dim3(NSTRIPE, NCHUNK, B_), dim3(64), 0, stream>>>(X, Y, ws, ws + 32);
    k_fin<<<1, 1, 0, stream>>>(ws + 32, (float*)d_out);
}